// Round 1
// baseline (1362.349 us; speedup 1.0000x reference)
//
#include <hip/hip_runtime.h>

#define LOG2E 1.44269504088896340736f

__device__ __forceinline__ float fast_sigmoid(float v) {
    // 1/(1+exp(-v)) via native exp2/rcp
    return __builtin_amdgcn_rcpf(1.0f + __builtin_amdgcn_exp2f(-LOG2E * v));
}
__device__ __forceinline__ float fast_tanh(float v) {
    // tanh(v) = 1 - 2/(exp(2v)+1)
    return 1.0f - 2.0f * __builtin_amdgcn_rcpf(1.0f + __builtin_amdgcn_exp2f(2.0f * LOG2E * v));
}

// One wave handles 2 batch elements; lane k owns hidden unit k.
// W_hh rows for lane k (4 gates x 64) live permanently in 256 VGPRs.
// h is exchanged wave-locally through ping-pong LDS buffers (no barriers).
__global__ void __launch_bounds__(256, 1)
lstm_fused(const float* __restrict__ x,      // [2048,512,1]
           const float* __restrict__ W_ih,   // [256,1]
           const float* __restrict__ W_hh,   // [256,64]
           const float* __restrict__ b_ih,   // [256]
           const float* __restrict__ b_hh,   // [256]
           const float* __restrict__ W_fc,   // [2,64]
           const float* __restrict__ b_fc,   // [2]
           float* __restrict__ out)          // [2048,2]
{
    constexpr int T = 512;
    __shared__ __align__(16) float hbuf[4][2][2][64];  // [wave][pingpong][nb][64]
    const int lane = threadIdx.x & 63;
    const int wid  = threadIdx.x >> 6;
    const int gw   = blockIdx.x * 4 + wid;   // global wave id: 0..1023
    const int b0   = gw * 2;
    const int b1   = b0 + 1;

    // ---- preload W_hh rows into registers (gate order i,f,g,o) ----
    float wi[64], wf[64], wg[64], wo[64];
    {
        const float* Wi = W_hh + (0 * 64 + lane) * 64;
        const float* Wf = W_hh + (1 * 64 + lane) * 64;
        const float* Wg = W_hh + (2 * 64 + lane) * 64;
        const float* Wo = W_hh + (3 * 64 + lane) * 64;
        #pragma unroll
        for (int j = 0; j < 64; j += 4) {
            *(float4*)&wi[j] = *(const float4*)&Wi[j];
            *(float4*)&wf[j] = *(const float4*)&Wf[j];
            *(float4*)&wg[j] = *(const float4*)&Wg[j];
            *(float4*)&wo[j] = *(const float4*)&Wo[j];
        }
    }
    const float wxi = W_ih[lane];
    const float wxf = W_ih[64 + lane];
    const float wxg = W_ih[128 + lane];
    const float wxo = W_ih[192 + lane];
    const float bsi = b_ih[lane]       + b_hh[lane];
    const float bsf = b_ih[64 + lane]  + b_hh[64 + lane];
    const float bsg = b_ih[128 + lane] + b_hh[128 + lane];
    const float bso = b_ih[192 + lane] + b_hh[192 + lane];

    // h starts at zero: init ping buffer 0
    hbuf[wid][0][0][lane] = 0.0f;
    hbuf[wid][0][1][lane] = 0.0f;

    float c0 = 0.0f, c1 = 0.0f;
    float h0 = 0.0f, h1 = 0.0f;

    const float* x0p = x + (long)b0 * T;
    const float* x1p = x + (long)b1 * T;

#define STEP(RB, WB, TT) do {                                                         \
    float sx0 = __builtin_bit_cast(float,                                             \
        __builtin_amdgcn_readlane(__builtin_bit_cast(int, xc0), (TT)));               \
    float sx1 = __builtin_bit_cast(float,                                             \
        __builtin_amdgcn_readlane(__builtin_bit_cast(int, xc1), (TT)));               \
    float ai0 = fmaf(sx0, wxi, bsi), af0 = fmaf(sx0, wxf, bsf);                       \
    float ag0 = fmaf(sx0, wxg, bsg), ao0 = fmaf(sx0, wxo, bso);                       \
    float ai1 = fmaf(sx1, wxi, bsi), af1 = fmaf(sx1, wxf, bsf);                       \
    float ag1 = fmaf(sx1, wxg, bsg), ao1 = fmaf(sx1, wxo, bso);                       \
    const float4* hA = (const float4*)&hbuf[wid][RB][0][0];                           \
    const float4* hB = (const float4*)&hbuf[wid][RB][1][0];                           \
    _Pragma("unroll")                                                                 \
    for (int jc = 0; jc < 16; ++jc) {                                                 \
        float4 hv0 = hA[jc];                                                          \
        float4 hv1 = hB[jc];                                                          \
        _Pragma("unroll")                                                             \
        for (int u = 0; u < 4; ++u) {                                                 \
            const int j = jc * 4 + u;                                                 \
            const float e0 = (&hv0.x)[u];                                             \
            const float e1 = (&hv1.x)[u];                                             \
            ai0 = fmaf(e0, wi[j], ai0); af0 = fmaf(e0, wf[j], af0);                   \
            ag0 = fmaf(e0, wg[j], ag0); ao0 = fmaf(e0, wo[j], ao0);                   \
            ai1 = fmaf(e1, wi[j], ai1); af1 = fmaf(e1, wf[j], af1);                   \
            ag1 = fmaf(e1, wg[j], ag1); ao1 = fmaf(e1, wo[j], ao1);                   \
        }                                                                             \
    }                                                                                 \
    float i0 = fast_sigmoid(ai0), f0 = fast_sigmoid(af0);                             \
    float g0 = fast_tanh(ag0),    o0 = fast_sigmoid(ao0);                             \
    float i1 = fast_sigmoid(ai1), f1 = fast_sigmoid(af1);                             \
    float g1 = fast_tanh(ag1),    o1 = fast_sigmoid(ao1);                             \
    c0 = fmaf(f0, c0, i0 * g0);                                                       \
    c1 = fmaf(f1, c1, i1 * g1);                                                       \
    h0 = o0 * fast_tanh(c0);                                                          \
    h1 = o1 * fast_tanh(c1);                                                          \
    hbuf[wid][WB][0][lane] = h0;                                                      \
    hbuf[wid][WB][1][lane] = h1;                                                      \
} while (0)

    for (int tb = 0; tb < T; tb += 64) {
        // coalesced x chunk: 64 timesteps per lane-register, broadcast via readlane
        float xc0 = x0p[tb + lane];
        float xc1 = x1p[tb + lane];
        for (int tt = 0; tt < 64; tt += 2) {
            STEP(0, 1, tt);       // even step: read buf0, write buf1
            STEP(1, 0, tt + 1);   // odd step:  read buf1, write buf0
        }
    }
#undef STEP

    // ---- epilogue: out[b,:] = h_T @ W_fc.T + b_fc ----
    const float wc0 = W_fc[lane];        // W_fc[0][lane]
    const float wc1 = W_fc[64 + lane];   // W_fc[1][lane]
    float p00 = h0 * wc0, p01 = h0 * wc1;
    float p10 = h1 * wc0, p11 = h1 * wc1;
    #pragma unroll
    for (int off = 32; off > 0; off >>= 1) {
        p00 += __shfl_down(p00, off);
        p01 += __shfl_down(p01, off);
        p10 += __shfl_down(p10, off);
        p11 += __shfl_down(p11, off);
    }
    if (lane == 0) {
        out[b0 * 2 + 0] = p00 + b_fc[0];
        out[b0 * 2 + 1] = p01 + b_fc[1];
        out[b1 * 2 + 0] = p10 + b_fc[0];
        out[b1 * 2 + 1] = p11 + b_fc[1];
    }
}

extern "C" void kernel_launch(void* const* d_in, const int* in_sizes, int n_in,
                              void* d_out, int out_size, void* d_ws, size_t ws_size,
                              hipStream_t stream) {
    const float* x    = (const float*)d_in[0];
    const float* W_ih = (const float*)d_in[1];
    const float* W_hh = (const float*)d_in[2];
    const float* b_ih = (const float*)d_in[3];
    const float* b_hh = (const float*)d_in[4];
    const float* W_fc = (const float*)d_in[5];
    const float* b_fc = (const float*)d_in[6];
    float* out = (float*)d_out;

    dim3 grid(256);    // 2048 batches / (2 per wave * 4 waves per block)
    dim3 block(256);
    hipLaunchKernelGGL(lstm_fused, grid, block, 0, stream,
                       x, W_ih, W_hh, b_ih, b_hh, W_fc, b_fc, out);
}

// Round 2
// 607.696 us; speedup vs baseline: 2.2418x; 2.2418x over previous
//
#include <hip/hip_runtime.h>

#define LOG2E 1.44269504088896340736f

__device__ __forceinline__ float fast_tanh(float v) {
    return 1.0f - 2.0f * __builtin_amdgcn_rcpf(1.0f + __builtin_amdgcn_exp2f(2.0f * LOG2E * v));
}

// Two waves per batch-pair (gate-split):
//   role 0: gates {i,f}  (W rows 0..127)   — owns batch 0's c/h recurrence
//   role 1: gates {g,o}  (W rows 128..255) — owns batch 1's c/h recurrence
// Each lane holds 128 W floats (2 rows of 64) -> no VGPR spill (cap is 256).
// Exchange of post-nonlinearity gate values + h through LDS, 2 barriers/step.
__global__ void __launch_bounds__(256, 2)
lstm_fused(const float* __restrict__ x,      // [2048,512,1]
           const float* __restrict__ W_ih,   // [256,1]
           const float* __restrict__ W_hh,   // [256,64]
           const float* __restrict__ b_ih,   // [256]
           const float* __restrict__ b_hh,   // [256]
           const float* __restrict__ W_fc,   // [2,64]
           const float* __restrict__ b_fc,   // [2]
           float* __restrict__ out)          // [2048,2]
{
    constexpr int T = 512;
    __shared__ __align__(16) float hbuf[2][2][64];     // [pair][batch][unit]
    __shared__ __align__(16) float exch[2][2][2][64];  // [pair][batch][g01][unit]

    const int lane = threadIdx.x & 63;
    const int wid  = threadIdx.x >> 6;
    const int pair = wid >> 1;        // 0,1 within block
    const int role = wid & 1;         // 0: i,f   1: g,o
    const int gp   = blockIdx.x * 2 + pair;   // global pair id 0..1023
    const int b0   = gp * 2;
    const int b1   = b0 + 1;

    // ---- W rows for this role (gate order i,f,g,o) ----
    const int rP = role * 128 + lane;        // i or g row
    const int rQ = role * 128 + 64 + lane;   // f or o row
    float wP[64], wQ[64];
    {
        const float* WP = W_hh + (long)rP * 64;
        const float* WQ = W_hh + (long)rQ * 64;
        #pragma unroll
        for (int j = 0; j < 64; j += 4) {
            *(float4*)&wP[j] = *(const float4*)&WP[j];
            *(float4*)&wQ[j] = *(const float4*)&WQ[j];
        }
    }
    const float wxP = W_ih[rP];
    const float wxQ = W_ih[rQ];
    const float bP  = b_ih[rP] + b_hh[rP];
    const float bQ  = b_ih[rQ] + b_hh[rQ];

    // Unified nonlinearity: n(v) = A + B * rcp(1 + exp2(k*v))
    //   sigmoid: k=-LOG2E, A=0, B=1    (role 0's P, and Q always)
    //   tanh:    k=+2LOG2E, A=1, B=-2  (role 1's P)
    const float kP = role ? (2.0f * LOG2E) : (-LOG2E);
    const float AP = role ? 1.0f : 0.0f;
    const float BP = role ? -2.0f : 1.0f;

    if (role == 0) {
        hbuf[pair][0][lane] = 0.0f;
        hbuf[pair][1][lane] = 0.0f;
    }
    __syncthreads();

    float c = 0.0f;     // cell state of the OWN batch (batch index == role)
    float hown = 0.0f;  // hidden state of own batch

    const float* x0p = x + (long)b0 * T;
    const float* x1p = x + (long)b1 * T;

    for (int tb = 0; tb < T; tb += 64) {
        // coalesced x chunk; broadcast per-step via readlane (uniform index)
        float xc0 = x0p[tb + lane];
        float xc1 = x1p[tb + lane];
        for (int tt = 0; tt < 64; ++tt) {
            float sx0 = __builtin_bit_cast(float,
                __builtin_amdgcn_readlane(__builtin_bit_cast(int, xc0), tt));
            float sx1 = __builtin_bit_cast(float,
                __builtin_amdgcn_readlane(__builtin_bit_cast(int, xc1), tt));

            float aP0 = fmaf(sx0, wxP, bP), aQ0 = fmaf(sx0, wxQ, bQ);
            float aP1 = fmaf(sx1, wxP, bP), aQ1 = fmaf(sx1, wxQ, bQ);

            // matvec over h (uniform-address broadcast reads from LDS)
            const float4* hA = (const float4*)&hbuf[pair][0][0];
            const float4* hB = (const float4*)&hbuf[pair][1][0];
            #pragma unroll
            for (int jc = 0; jc < 16; ++jc) {
                float4 hv0 = hA[jc];
                float4 hv1 = hB[jc];
                #pragma unroll
                for (int u = 0; u < 4; ++u) {
                    const int j = jc * 4 + u;
                    const float e0 = (&hv0.x)[u];
                    const float e1 = (&hv1.x)[u];
                    aP0 = fmaf(e0, wP[j], aP0); aQ0 = fmaf(e0, wQ[j], aQ0);
                    aP1 = fmaf(e1, wP[j], aP1); aQ1 = fmaf(e1, wQ[j], aQ1);
                }
            }

            // nonlinearities (P per role formula, Q always sigmoid)
            float nP0 = fmaf(BP, __builtin_amdgcn_rcpf(1.0f + __builtin_amdgcn_exp2f(kP * aP0)), AP);
            float nP1 = fmaf(BP, __builtin_amdgcn_rcpf(1.0f + __builtin_amdgcn_exp2f(kP * aP1)), AP);
            float nQ0 = __builtin_amdgcn_rcpf(1.0f + __builtin_amdgcn_exp2f(-LOG2E * aQ0));
            float nQ1 = __builtin_amdgcn_rcpf(1.0f + __builtin_amdgcn_exp2f(-LOG2E * aQ1));

            // own batch = role; other batch = 1-role
            const float nPo = role ? nP0 : nP1;   // for other batch
            const float nQo = role ? nQ0 : nQ1;
            const float nPn = role ? nP1 : nP0;   // own
            const float nQn = role ? nQ1 : nQ0;

            exch[pair][1 - role][0][lane] = nPo;
            exch[pair][1 - role][1][lane] = nQo;
            __syncthreads();

            const float m0 = exch[pair][role][0][lane];
            const float m1 = exch[pair][role][1][lane];
            // role 0: i=nPn f=nQn g=m0  o=m1
            // role 1: i=m0  f=m1  g=nPn o=nQn
            const float ig = role ? m0  : nPn;
            const float fg = role ? m1  : nQn;
            const float gg = role ? nPn : m0;
            const float og = role ? nQn : m1;

            c    = fmaf(fg, c, ig * gg);
            hown = og * fast_tanh(c);
            hbuf[pair][role][lane] = hown;
            __syncthreads();
        }
    }

    // ---- epilogue: out[b_own,:] = h_own @ W_fc.T + b_fc ----
    const int   bown = gp * 2 + role;
    const float wc0  = W_fc[lane];
    const float wc1  = W_fc[64 + lane];
    float p0 = hown * wc0;
    float p1 = hown * wc1;
    #pragma unroll
    for (int off = 32; off > 0; off >>= 1) {
        p0 += __shfl_down(p0, off);
        p1 += __shfl_down(p1, off);
    }
    if (lane == 0) {
        out[bown * 2 + 0] = p0 + b_fc[0];
        out[bown * 2 + 1] = p1 + b_fc[1];
    }
}

extern "C" void kernel_launch(void* const* d_in, const int* in_sizes, int n_in,
                              void* d_out, int out_size, void* d_ws, size_t ws_size,
                              hipStream_t stream) {
    const float* x    = (const float*)d_in[0];
    const float* W_ih = (const float*)d_in[1];
    const float* W_hh = (const float*)d_in[2];
    const float* b_ih = (const float*)d_in[3];
    const float* b_hh = (const float*)d_in[4];
    const float* W_fc = (const float*)d_in[5];
    const float* b_fc = (const float*)d_in[6];
    float* out = (float*)d_out;

    dim3 grid(512);    // 1024 batch-pairs, 2 pairs (4 waves) per block
    dim3 block(256);
    hipLaunchKernelGGL(lstm_fused, grid, block, 0, stream,
                       x, W_ih, W_hh, b_ih, b_hh, W_fc, b_fc, out);
}